// Round 6
// baseline (297.158 us; speedup 1.0000x reference)
//
#include <hip/hip_runtime.h>
#include <math.h>

#define HID 256
#define SEQ 512

typedef float v4f __attribute__((ext_vector_type(4)));
typedef float v2f __attribute__((ext_vector_type(2)));

// ---------------------------------------------------------------------------
// Phase 1: inp[t][i] = b[i] + sum_j emb[idx[t]][j] * W[i][HID + j]
// One block per timestep t (512 blocks), 256 threads (one per output i).
// ---------------------------------------------------------------------------
__global__ __launch_bounds__(256) void qrnn_phase1(
    const int* __restrict__ idx, const float* __restrict__ emb,
    const float* __restrict__ W, const float* __restrict__ b,
    float* __restrict__ inp)
{
    const int t = blockIdx.x;
    const int i = threadIdx.x;
    __shared__ float xs[HID];
    const size_t row = (size_t)idx[t];
    xs[i] = emb[row * HID + i];
    __syncthreads();

    const float* wr = W + (size_t)i * (2 * HID) + HID;  // Wx row i
    float acc = b[i];
#pragma unroll
    for (int k = 0; k < HID / 4; ++k) {
        const float4 w4 = *reinterpret_cast<const float4*>(wr + k * 4);
        const float4 x4 = *reinterpret_cast<const float4*>(&xs[k * 4]);
        acc = fmaf(w4.x, x4.x, acc);
        acc = fmaf(w4.y, x4.y, acc);
        acc = fmaf(w4.z, x4.z, acc);
        acc = fmaf(w4.w, x4.w, acc);
    }
    inp[t * HID + i] = acc;
}

// DPP add across lanes — all three ctrls are SELF-INVERSE (direction-proof):
// 0xB1 quad_perm(1,0,3,2)=xor1; 0x4E quad_perm(2,3,0,1)=xor2;
// 0x141 row_half_mirror = xor7 within each aligned 8-lane group.
template <int CTRL>
__device__ __forceinline__ float dpp_add(float v)
{
    int x = __builtin_amdgcn_update_dpp(0, __float_as_int(v), CTRL, 0xF, 0xF, true);
    return v + __int_as_float(x);
}

// Pin a row of 8 v4f into VGPRs (anti-rematerialization).
#define PIN8(a) asm volatile("" : "+v"(a[0]), "+v"(a[1]), "+v"(a[2]), \
                                  "+v"(a[3]), "+v"(a[4]), "+v"(a[5]), \
                                  "+v"(a[6]), "+v"(a[7]))

// Packed f32 FMA: acc.{lo,hi} += w.{lo,hi} * h.{lo,hi}. One VOP3P instr does
// 2 FMAs/lane — this is the only way to the 157 TF f32 vector rate; the
// compiler never auto-emits it. Non-volatile: pure dataflow, scheduler may
// interleave independent chains. "v" operands force VGPR residency at use.
__device__ __forceinline__ void pk_fma(v2f& acc, v2f w, v2f h)
{
    asm("v_pk_fma_f32 %0, %1, %2, %0" : "+v"(acc) : "v"(w), "v"(h));
}

// ---------------------------------------------------------------------------
// Phase 2: sequential scan, single block of 512 threads (8 waves, 2/SIMD).
// Round-3 proven layout (0 bank conflicts): g = tid>>3 (64 groups of 8
// lanes), r = tid&7. Group g owns rows [4g,4g+4); lane r owns cols
// [32r,32r+32). Weight tile 4x32 = 128 floats = 64 VGPR pairs per thread.
// h double-buffered in LDS, word-swizzle sw(w) = w ^ (((w>>5)&7)<<2):
// the 8 distinct float4 read addrs hit 8 distinct bank quads (conflict-free,
// measured 0 in round 3); 16-lane-group variant (round 5) necessarily
// 2-way aliases -> reverted.
// FMA inner loop uses v_pk_fma_f32 (64 instrs/step vs 128 scalar fmaf).
// Reduction: 3-stage self-inverse DPP butterfly over the 8-lane group,
// then a 3-level cndmask mux picks row m = r&3; lanes r<4 write.
// ---------------------------------------------------------------------------
__global__ void __launch_bounds__(512)
__attribute__((amdgpu_waves_per_eu(2, 2)))
qrnn_phase2(const float* __restrict__ W, const float* __restrict__ inp,
            float* __restrict__ out)
{
    const int tid = threadIdx.x;
    const int r = tid & 7;
    const int g = tid >> 3;     // [0, 64)
    const int m_out = r & 3;
    const int i_out = 4 * g + m_out;

    __shared__ float hbuf[2][HID];
    if (tid < HID) hbuf[0][tid] = 0.0f;

    // Weight tile: wv[m][k] = W[(4g+m)][32r + 4k .. +3]  (Wh part, cols<HID)
    v4f wv[4][8];
#pragma unroll
    for (int m = 0; m < 4; ++m) {
        const float* wrow = W + (size_t)(4 * g + m) * (2 * HID) + r * 32;
#pragma unroll
        for (int k = 0; k < 8; ++k)
            wv[m][k] = *reinterpret_cast<const v4f*>(wrow + k * 4);
        PIN8(wv[m]);
    }

    // Loop-invariant swizzled word offsets (round-3 pattern, conflict-free)
    int rdoff[8];
#pragma unroll
    for (int k = 0; k < 8; ++k)
        rdoff[k] = r * 32 + (((k ^ r) & 7) << 2);
    const int wroff = i_out ^ (((i_out >> 5) & 7) << 2);

    float ip = inp[i_out];  // inp[0][i_out]
    float h = 0.0f;
    __syncthreads();

    auto step = [&](const float* __restrict__ src, float* __restrict__ dst,
                    int tnext) {
        // This lane's 32 h values: 8 swizzled float4 reads, conflict-free
        v4f h4[8];
#pragma unroll
        for (int k = 0; k < 8; ++k)
            h4[k] = *reinterpret_cast<const v4f*>(src + rdoff[k]);

        // Prefetch next step's inp (branchless; hidden under FMAs)
        float ip_next = inp[(tnext & (SEQ - 1)) * HID + i_out];

        // 4 partial dots, 16 packed FMAs each (64 pk_fma total = 128 MACs)
        v2f acc2[4];
#pragma unroll
        for (int m = 0; m < 4; ++m) {
            acc2[m].x = 0.0f; acc2[m].y = 0.0f;
#pragma unroll
            for (int k = 0; k < 8; ++k) {
                v2f wlo = { wv[m][k].x, wv[m][k].y };
                v2f whi = { wv[m][k].z, wv[m][k].w };
                v2f hlo = { h4[k].x, h4[k].y };
                v2f hhi = { h4[k].z, h4[k].w };
                pk_fma(acc2[m], wlo, hlo);
                pk_fma(acc2[m], whi, hhi);
            }
        }
        float acc[4];
#pragma unroll
        for (int m = 0; m < 4; ++m)
            acc[m] = acc2[m].x + acc2[m].y;

        // Butterfly reduce across the 8-lane group (self-inverse DPP only)
#pragma unroll
        for (int m = 0; m < 4; ++m) {
            acc[m] = dpp_add<0xB1>(acc[m]);   // xor 1
            acc[m] = dpp_add<0x4E>(acc[m]);   // xor 2
            acc[m] = dpp_add<0x141>(acc[m]);  // xor 7
        }

        // Lane picks its row (lanes r and r+4 duplicate row r&3)
        float s0 = (r & 1) ? acc[1] : acc[0];
        float s1 = (r & 1) ? acc[3] : acc[2];
        float d  = (r & 2) ? s1 : s0;

        d += ip;
        // tanh(d) = 1 - 2/(exp(2d)+1)
        float e = __expf(2.0f * d);
        h = 1.0f - 2.0f / (e + 1.0f);

        // Writer lanes (r<4) store h_new[i_out]; 32 swizzled words per wave
        // cover all 32 banks -> conflict-free (round-3 measured 0).
        if (r < 4) dst[wroff] = h;

        ip = ip_next;
        __syncthreads();
    };

#pragma unroll 1
    for (int t = 0; t < SEQ; t += 2) {
        step(&hbuf[0][0], &hbuf[1][0], t + 1);
        step(&hbuf[1][0], &hbuf[0][0], t + 2);
    }

    if (r < 4) out[i_out] = h;
}

extern "C" void kernel_launch(void* const* d_in, const int* in_sizes, int n_in,
                              void* d_out, int out_size, void* d_ws, size_t ws_size,
                              hipStream_t stream)
{
    const int*   idx = (const int*)d_in[0];
    const float* emb = (const float*)d_in[1];
    const float* W   = (const float*)d_in[2];
    const float* b   = (const float*)d_in[3];
    float* out = (float*)d_out;
    float* inp = (float*)d_ws;  // SEQ*HID*4 = 512 KB scratch

    qrnn_phase1<<<SEQ, HID, 0, stream>>>(idx, emb, W, b, inp);
    qrnn_phase2<<<1, 512, 0, stream>>>(W, inp, out);
}